// Round 13
// baseline (99.335 us; speedup 1.0000x reference)
//
#include <hip/hip_runtime.h>

#define DIM 512
#define HIDDEN 1024
#define H2 2048        // 2*HIDDEN
#define NEXP 32
#define TOPK 4
#define TOKENS 64
#define NPAIR (TOKENS*TOPK)   // 256
#define PADK 8                // ushort pad per LDS row (2-way bank alias = free)

typedef __attribute__((ext_vector_type(8))) short short8;
typedef __attribute__((ext_vector_type(4))) float fp32x4;
typedef __attribute__((ext_vector_type(4))) unsigned short ushort4v;
typedef __attribute__((ext_vector_type(2))) unsigned short ushort2v;

// f32 -> bf16 round-nearest-even
__device__ __forceinline__ unsigned short f2bf_rne(float f) {
    unsigned u = __float_as_uint(f);
    return (unsigned short)((u + 0x7FFFu + ((u >> 16) & 1u)) >> 16);
}
// f32 -> packed (hi | lo<<16): hi = truncate-to-bf16, lo = RNE(residual)
__device__ __forceinline__ unsigned split2p(float f) {
    unsigned u = __float_as_uint(f);
    unsigned short h = (unsigned short)(u >> 16);
    float hf = __uint_as_float(u & 0xFFFF0000u);
    unsigned short lo = f2bf_rne(f - hf);
    return (unsigned)h | ((unsigned)lo << 16);
}
__device__ __forceinline__ float dot4f(float4 a, float4 b) {
    return a.x*b.x + a.y*b.y + a.z*b.z + a.w*b.w;
}
// swiglu pair: gv from even h, lv from odd h
__device__ __forceinline__ float swiglu2(float he, float ho) {
    float gv = fminf(he, 7.f);
    float lv = fminf(fmaxf(ho, -7.f), 7.f);
    float sg = 1.f / (1.f + __expf(-1.702f * gv));
    return gv * sg * (lv + 1.f);
}

// split ca,cb float4 -> A-frags (hi, lo) and run 2 MFMAs against LDS B-frag
#define MFMA_STEP(xbuf, ca, cb, kt) do {                                      \
    short8 ah, al; unsigned pk;                                               \
    pk = split2p((ca).x); ah[0]=(short)(pk & 0xFFFF); al[0]=(short)(pk >> 16);\
    pk = split2p((ca).y); ah[1]=(short)(pk & 0xFFFF); al[1]=(short)(pk >> 16);\
    pk = split2p((ca).z); ah[2]=(short)(pk & 0xFFFF); al[2]=(short)(pk >> 16);\
    pk = split2p((ca).w); ah[3]=(short)(pk & 0xFFFF); al[3]=(short)(pk >> 16);\
    pk = split2p((cb).x); ah[4]=(short)(pk & 0xFFFF); al[4]=(short)(pk >> 16);\
    pk = split2p((cb).y); ah[5]=(short)(pk & 0xFFFF); al[5]=(short)(pk >> 16);\
    pk = split2p((cb).z); ah[6]=(short)(pk & 0xFFFF); al[6]=(short)(pk >> 16);\
    pk = split2p((cb).w); ah[7]=(short)(pk & 0xFFFF); al[7]=(short)(pk >> 16);\
    short8 bh = *(const short8*)&xbuf[lr][(kt)*32 + lg*8];                    \
    acc = __builtin_amdgcn_mfma_f32_16x16x32_bf16(ah, bh, acc, 0, 0, 0);      \
    acc = __builtin_amdgcn_mfma_f32_16x16x32_bf16(al, bh, acc, 0, 0, 0);      \
} while (0)

// ---------------- router: 16-way split-K logits + top4 + softmax ----------
// 64 blocks x 512 thr. Also zeroes out[b][:] for the fused atomic combine.
__global__ __launch_bounds__(512) void router_kernel(
        const float* __restrict__ x, const float* __restrict__ Wg,
        const float* __restrict__ bg, int* __restrict__ idxw,
        float* __restrict__ eww, float* __restrict__ out) {
    int b = blockIdx.x;
    int tid = threadIdx.x;
    int e = tid >> 4, s = tid & 15;
    __shared__ float xs[DIM];
    __shared__ float g[NEXP];
    if (tid < DIM/4) {
        *(float4*)&xs[4*tid] = *(const float4*)(x + (size_t)b*DIM + 4*tid);
    }
    if (tid >= 128 && tid < 256) {
        int i = tid - 128;
        *(float4*)(out + (size_t)b*DIM + 4*i) = make_float4(0.f,0.f,0.f,0.f);
    }
    __syncthreads();
    const float* wr = Wg + e*DIM;
    float acc = 0.f;
    #pragma unroll
    for (int i = 0; i < 8; ++i) {
        int d4 = s + 16*i;
        float4 wv = *(const float4*)(wr + 4*d4);
        float4 xv = *(const float4*)&xs[4*d4];
        acc += dot4f(wv, xv);
    }
    #pragma unroll
    for (int m = 1; m < 16; m <<= 1) acc += __shfl_xor(acc, m);
    if (s == 0) g[e] = acc + bg[e];
    __syncthreads();
    if (tid == 0) {
        int sel[TOPK]; float val[TOPK];
        bool used[NEXP];
        for (int i = 0; i < NEXP; ++i) used[i] = false;
        for (int k = 0; k < TOPK; ++k) {
            float best = -1e30f; int bi = 0;
            for (int ee = 0; ee < NEXP; ++ee) {
                if (!used[ee] && g[ee] > best) { best = g[ee]; bi = ee; }
            }
            used[bi] = true; sel[k] = bi; val[k] = best;
        }
        float m = val[0];
        float p[TOPK]; float sum = 0.f;
        for (int k = 0; k < TOPK; ++k) { p[k] = __expf(val[k] - m); sum += p[k]; }
        float inv = 1.f / sum;
        for (int k = 0; k < TOPK; ++k) {
            idxw[b*TOPK + k] = sel[k];
            eww[b*TOPK + k]  = p[k] * inv;
        }
    }
}

// Ballot-based deterministic per-expert list build. Caller: 256 threads.
__device__ __forceinline__ int build_list_ballot(
        const int* __restrict__ idxw, int e, int tid,
        int* slist, unsigned long long* smask, int* scnt) {
    int me = idxw[tid];
    unsigned long long m = __ballot(me == e);
    int l = tid & 63, w = tid >> 6;
    if (l == 0) smask[w] = m;
    __syncthreads();
    if (me == e) {
        int r = __popcll(m & ((1ull << l) - 1ull));
        #pragma unroll
        for (int q = 0; q < 4; ++q) r += (q < w) ? __popcll(smask[q]) : 0;
        slist[r] = tid;
    }
    if (tid == 0) {
        *scnt = __popcll(smask[0]) + __popcll(smask[1])
              + __popcll(smask[2]) + __popcll(smask[3]);
    }
    __syncthreads();
    return *scnt;
}

// ---------------- expert up-proj (MFMA, k-split x2 over D) ----------------
// block = 256 thr = 4 waves; wave owns 16 raw w1 rows x 16 tokens x D/2.
// grid (NEXP, H2/64 = 32, 2). Partials -> hbuf (h0 or h1); kz0 carries b1.
__global__ __launch_bounds__(256, 8) void expert_up(
        const float* __restrict__ x, const float* __restrict__ w1,
        const float* __restrict__ b1, const int* __restrict__ idxw,
        float* __restrict__ h0, float* __restrict__ h1) {
    int e = blockIdx.x;
    int kz = blockIdx.z;
    int tid = threadIdx.x;
    __shared__ int slist[TOKENS];
    __shared__ unsigned long long smask[4];
    __shared__ int scnt;
    int n = build_list_ballot(idxw, e, tid, slist, smask, &scnt);
    if (n == 0) return;
    int wv = tid >> 6, l = tid & 63;
    int lr = l & 15, lg = l >> 4;
    __shared__ unsigned short xh[16][256 + PADK];   // 8.25 KB (this D-half)
    int r0 = blockIdx.y * 64 + wv * 16;    // raw row tile base (0..2047)
    const float4* w4 = (const float4*)(w1 + ((size_t)e*H2 + r0 + lr) * DIM
                                       + kz * 256 + lg * 8);
    float* hbuf = kz ? h1 : h0;

    for (int t0 = 0; t0 < n; t0 += 16) {
        int nn = min(16, n - t0);
        __syncthreads();
        for (int i = tid; i < 16 * 64; i += 256) {       // 64 f4 per half-row
            int j = i >> 6, dd = i & 63;
            float4 v = make_float4(0.f, 0.f, 0.f, 0.f);
            if (j < nn) {
                int p = slist[t0 + j];
                v = *(const float4*)(x + (size_t)(p >> 2)*DIM + kz*256 + 4*dd);
            }
            ushort4v hv;
            hv[0] = f2bf_rne(v.x); hv[1] = f2bf_rne(v.y);
            hv[2] = f2bf_rne(v.z); hv[3] = f2bf_rne(v.w);
            *(ushort4v*)&xh[j][4*dd] = hv;
        }
        __syncthreads();

        fp32x4 acc = {0.f, 0.f, 0.f, 0.f};
        float4 c0 = w4[0], c1 = w4[1];
        for (int kt = 0; kt < 8; ++kt) {
            int ktn = (kt + 1) & 7;          // branchless wrap
            float4 n0 = w4[8*ktn], n1 = w4[8*ktn + 1];
            MFMA_STEP(xh, c0, c1, kt);
            c0 = n0; c1 = n1;
        }

        // D: col = l&15 = token, row = (l>>4)*4 + reg
        int tok = lr;
        if (tok < nn) {
            int p = slist[t0 + tok];
            #pragma unroll
            for (int u = 0; u < 4; ++u) {
                int rr = r0 + lg*4 + u;
                float v = acc[u] + (kz == 0 ? b1[e*H2 + rr] : 0.f);
                hbuf[(size_t)p*H2 + rr] = v;
            }
        }
    }
}

// ---------------- expert down-proj + swiglu-in-staging + fused combine ----
// block = 256 thr = 4 waves; wave owns 16 w2 rows x 16 tokens x HIDDEN/4.
// grid (NEXP, DIM/64 = 8, 4). Staging reads h0+h1, applies swiglu, bf16.
__global__ __launch_bounds__(256, 4) void expert_down(
        const float* __restrict__ h0, const float* __restrict__ h1,
        const float* __restrict__ w2, const float* __restrict__ b2,
        const int* __restrict__ idxw, const float* __restrict__ eww,
        float* __restrict__ out) {
    int e = blockIdx.x;
    int kz = blockIdx.z;                   // HIDDEN quarter: 0..3
    int tid = threadIdx.x;
    __shared__ int slist[TOKENS];
    __shared__ unsigned long long smask[4];
    __shared__ int scnt;
    int n = build_list_ballot(idxw, e, tid, slist, smask, &scnt);
    if (n == 0) return;
    int wv = tid >> 6, l = tid & 63;
    int lr = l & 15, lg = l >> 4;
    __shared__ unsigned short as_[16][256 + PADK];   // 8.25 KB (this quarter)
    int r0 = blockIdx.y * 64 + wv * 16;    // output row tile base (0..511)
    const float4* w4 = (const float4*)(w2 + ((size_t)e*DIM + r0 + lr) * HIDDEN
                                       + kz * 256 + lg * 8);

    for (int t0 = 0; t0 < n; t0 += 16) {
        int nn = min(16, n - t0);
        __syncthreads();
        // stage quarter: act[c] = swiglu(h[2c], h[2c+1]), c in [kz*256, +256)
        for (int i = tid; i < 16 * 128; i += 256) {      // 128 h-f4 per quarter
            int j = i >> 7, dd = i & 127;
            float4 a = make_float4(0.f, 0.f, 0.f, 0.f);
            if (j < nn) {
                int p = slist[t0 + j];
                size_t off = (size_t)p*H2 + kz*512 + 4*dd;
                float4 va = *(const float4*)(h0 + off);
                float4 vb = *(const float4*)(h1 + off);
                a.x = va.x + vb.x; a.y = va.y + vb.y;
                a.z = va.z + vb.z; a.w = va.w + vb.w;
            }
            ushort2v hv;
            hv[0] = f2bf_rne(swiglu2(a.x, a.y));
            hv[1] = f2bf_rne(swiglu2(a.z, a.w));
            *(ushort2v*)&as_[j][2*dd] = hv;
        }
        __syncthreads();

        fp32x4 acc = {0.f, 0.f, 0.f, 0.f};
        float4 c0 = w4[0], c1 = w4[1];
        for (int kt = 0; kt < 8; ++kt) {
            int ktn = (kt + 1) & 7;          // branchless wrap
            float4 n0 = w4[8*ktn], n1 = w4[8*ktn + 1];
            MFMA_STEP(as_, c0, c1, kt);
            c0 = n0; c1 = n1;
        }

        int tok = lr;
        if (tok < nn) {
            int p = slist[t0 + tok];
            float ew = eww[p];
            int b = p >> 2;
            #pragma unroll
            for (int u = 0; u < 4; ++u) {
                int rr = r0 + lg*4 + u;
                float v = acc[u] + (kz == 0 ? b2[e*DIM + rr] : 0.f);
                atomicAdd(out + (size_t)b*DIM + rr, ew * v);
            }
        }
    }
}

extern "C" void kernel_launch(void* const* d_in, const int* in_sizes, int n_in,
                              void* d_out, int out_size, void* d_ws, size_t ws_size,
                              hipStream_t stream) {
    const float* x  = (const float*)d_in[0];
    const float* Wg = (const float*)d_in[1];
    const float* bg = (const float*)d_in[2];
    const float* w1 = (const float*)d_in[3];
    const float* b1 = (const float*)d_in[4];
    const float* w2 = (const float*)d_in[5];
    const float* b2 = (const float*)d_in[6];
    float* out = (float*)d_out;

    char* ws = (char*)d_ws;
    int*   idxw = (int*)(ws);                   // 256 ints
    float* eww  = (float*)(ws + 1024);          // 256 floats
    float* h0   = (float*)(ws + 16384);                          // 256*2048 f32 = 2 MB
    float* h1   = (float*)(ws + 16384 + (size_t)NPAIR*H2*4);     // 2 MB

    router_kernel<<<TOKENS, 512, 0, stream>>>(x, Wg, bg, idxw, eww, out);
    expert_up<<<dim3(NEXP, H2/64, 2), 256, 0, stream>>>(x, w1, b1, idxw, h0, h1);
    expert_down<<<dim3(NEXP, DIM/64, 4), 256, 0, stream>>>(h0, h1, w2, b2, idxw, eww, out);
}

// Round 14
// 59.529 us; speedup vs baseline: 1.6687x; 1.6687x over previous
//
#include <hip/hip_runtime.h>

#define DIM 512
#define HIDDEN 1024
#define H2 2048        // 2*HIDDEN
#define NEXP 32
#define TOPK 4
#define TOKENS 64
#define NPAIR (TOKENS*TOPK)   // 256
#define PADK 8                // ushort pad per LDS row (2-way bank alias = free)

typedef __attribute__((ext_vector_type(8))) short short8;
typedef __attribute__((ext_vector_type(4))) float fp32x4;
typedef __attribute__((ext_vector_type(4))) unsigned short ushort4v;
typedef __attribute__((ext_vector_type(2))) unsigned short ushort2v;

// f32 -> bf16 round-nearest-even
__device__ __forceinline__ unsigned short f2bf_rne(float f) {
    unsigned u = __float_as_uint(f);
    return (unsigned short)((u + 0x7FFFu + ((u >> 16) & 1u)) >> 16);
}
// f32 -> packed (hi | lo<<16): hi = truncate-to-bf16, lo = RNE(residual)
__device__ __forceinline__ unsigned split2p(float f) {
    unsigned u = __float_as_uint(f);
    unsigned short h = (unsigned short)(u >> 16);
    float hf = __uint_as_float(u & 0xFFFF0000u);
    unsigned short lo = f2bf_rne(f - hf);
    return (unsigned)h | ((unsigned)lo << 16);
}
__device__ __forceinline__ float dot4f(float4 a, float4 b) {
    return a.x*b.x + a.y*b.y + a.z*b.z + a.w*b.w;
}
// swiglu pair: gv from even h, lv from odd h
__device__ __forceinline__ float swiglu2(float he, float ho) {
    float gv = fminf(he, 7.f);
    float lv = fminf(fmaxf(ho, -7.f), 7.f);
    float sg = 1.f / (1.f + __expf(-1.702f * gv));
    return gv * sg * (lv + 1.f);
}

// split ca,cb float4 -> A-frags (hi, lo) and run 2 MFMAs against LDS B-frag
#define MFMA_STEP(xbuf, ca, cb, kt) do {                                      \
    short8 ah, al; unsigned pk;                                               \
    pk = split2p((ca).x); ah[0]=(short)(pk & 0xFFFF); al[0]=(short)(pk >> 16);\
    pk = split2p((ca).y); ah[1]=(short)(pk & 0xFFFF); al[1]=(short)(pk >> 16);\
    pk = split2p((ca).z); ah[2]=(short)(pk & 0xFFFF); al[2]=(short)(pk >> 16);\
    pk = split2p((ca).w); ah[3]=(short)(pk & 0xFFFF); al[3]=(short)(pk >> 16);\
    pk = split2p((cb).x); ah[4]=(short)(pk & 0xFFFF); al[4]=(short)(pk >> 16);\
    pk = split2p((cb).y); ah[5]=(short)(pk & 0xFFFF); al[5]=(short)(pk >> 16);\
    pk = split2p((cb).z); ah[6]=(short)(pk & 0xFFFF); al[6]=(short)(pk >> 16);\
    pk = split2p((cb).w); ah[7]=(short)(pk & 0xFFFF); al[7]=(short)(pk >> 16);\
    short8 bh = *(const short8*)&xbuf[lr][(kt)*32 + lg*8];                    \
    acc = __builtin_amdgcn_mfma_f32_16x16x32_bf16(ah, bh, acc, 0, 0, 0);      \
    acc = __builtin_amdgcn_mfma_f32_16x16x32_bf16(al, bh, acc, 0, 0, 0);      \
} while (0)

// ---------------- router: 16-way split-K logits + top4 + softmax ----------
// 64 blocks x 512 thr. Also zeroes out[b][:] for the fused atomic combine.
__global__ __launch_bounds__(512) void router_kernel(
        const float* __restrict__ x, const float* __restrict__ Wg,
        const float* __restrict__ bg, int* __restrict__ idxw,
        float* __restrict__ eww, float* __restrict__ out) {
    int b = blockIdx.x;
    int tid = threadIdx.x;
    int e = tid >> 4, s = tid & 15;
    __shared__ float xs[DIM];
    __shared__ float g[NEXP];
    if (tid < DIM/4) {
        *(float4*)&xs[4*tid] = *(const float4*)(x + (size_t)b*DIM + 4*tid);
    }
    if (tid >= 128 && tid < 256) {
        int i = tid - 128;
        *(float4*)(out + (size_t)b*DIM + 4*i) = make_float4(0.f,0.f,0.f,0.f);
    }
    __syncthreads();
    const float* wr = Wg + e*DIM;
    float acc = 0.f;
    #pragma unroll
    for (int i = 0; i < 8; ++i) {
        int d4 = s + 16*i;
        float4 wv = *(const float4*)(wr + 4*d4);
        float4 xv = *(const float4*)&xs[4*d4];
        acc += dot4f(wv, xv);
    }
    #pragma unroll
    for (int m = 1; m < 16; m <<= 1) acc += __shfl_xor(acc, m);
    if (s == 0) g[e] = acc + bg[e];
    __syncthreads();
    if (tid == 0) {
        int sel[TOPK]; float val[TOPK];
        bool used[NEXP];
        for (int i = 0; i < NEXP; ++i) used[i] = false;
        for (int k = 0; k < TOPK; ++k) {
            float best = -1e30f; int bi = 0;
            for (int ee = 0; ee < NEXP; ++ee) {
                if (!used[ee] && g[ee] > best) { best = g[ee]; bi = ee; }
            }
            used[bi] = true; sel[k] = bi; val[k] = best;
        }
        float m = val[0];
        float p[TOPK]; float sum = 0.f;
        for (int k = 0; k < TOPK; ++k) { p[k] = __expf(val[k] - m); sum += p[k]; }
        float inv = 1.f / sum;
        for (int k = 0; k < TOPK; ++k) {
            idxw[b*TOPK + k] = sel[k];
            eww[b*TOPK + k]  = p[k] * inv;
        }
    }
}

// Ballot-based deterministic per-expert list build. Caller: 256 threads.
__device__ __forceinline__ int build_list_ballot(
        const int* __restrict__ idxw, int e, int tid,
        int* slist, unsigned long long* smask, int* scnt) {
    int me = idxw[tid];
    unsigned long long m = __ballot(me == e);
    int l = tid & 63, w = tid >> 6;
    if (l == 0) smask[w] = m;
    __syncthreads();
    if (me == e) {
        int r = __popcll(m & ((1ull << l) - 1ull));
        #pragma unroll
        for (int q = 0; q < 4; ++q) r += (q < w) ? __popcll(smask[q]) : 0;
        slist[r] = tid;
    }
    if (tid == 0) {
        *scnt = __popcll(smask[0]) + __popcll(smask[1])
              + __popcll(smask[2]) + __popcll(smask[3]);
    }
    __syncthreads();
    return *scnt;
}

// ---------------- expert up-proj (MFMA, k-split x2 over D) ----------------
// block = 256 thr = 4 waves; wave owns 16 raw w1 rows x 16 tokens x D/2.
// grid (NEXP, H2/64 = 32, 2). Partials -> hbuf (h0 or h1); kz0 carries b1.
// NOTE: (256,4) not (256,8) — the 8 cap forced VGPR=32 and spilled (R13).
__global__ __launch_bounds__(256, 4) void expert_up(
        const float* __restrict__ x, const float* __restrict__ w1,
        const float* __restrict__ b1, const int* __restrict__ idxw,
        float* __restrict__ h0, float* __restrict__ h1) {
    int e = blockIdx.x;
    int kz = blockIdx.z;
    int tid = threadIdx.x;
    __shared__ int slist[TOKENS];
    __shared__ unsigned long long smask[4];
    __shared__ int scnt;
    int n = build_list_ballot(idxw, e, tid, slist, smask, &scnt);
    if (n == 0) return;
    int wv = tid >> 6, l = tid & 63;
    int lr = l & 15, lg = l >> 4;
    __shared__ unsigned short xh[16][256 + PADK];   // 8.25 KB (this D-half)
    int r0 = blockIdx.y * 64 + wv * 16;    // raw row tile base (0..2047)
    const float4* w4 = (const float4*)(w1 + ((size_t)e*H2 + r0 + lr) * DIM
                                       + kz * 256 + lg * 8);
    float* hbuf = kz ? h1 : h0;

    for (int t0 = 0; t0 < n; t0 += 16) {
        int nn = min(16, n - t0);
        __syncthreads();
        for (int i = tid; i < 16 * 64; i += 256) {       // 64 f4 per half-row
            int j = i >> 6, dd = i & 63;
            float4 v = make_float4(0.f, 0.f, 0.f, 0.f);
            if (j < nn) {
                int p = slist[t0 + j];
                v = *(const float4*)(x + (size_t)(p >> 2)*DIM + kz*256 + 4*dd);
            }
            ushort4v hv;
            hv[0] = f2bf_rne(v.x); hv[1] = f2bf_rne(v.y);
            hv[2] = f2bf_rne(v.z); hv[3] = f2bf_rne(v.w);
            *(ushort4v*)&xh[j][4*dd] = hv;
        }
        __syncthreads();

        fp32x4 acc = {0.f, 0.f, 0.f, 0.f};
        float4 c0 = w4[0], c1 = w4[1];
        for (int kt = 0; kt < 8; ++kt) {
            int ktn = (kt + 1) & 7;          // branchless wrap
            float4 n0 = w4[8*ktn], n1 = w4[8*ktn + 1];
            MFMA_STEP(xh, c0, c1, kt);
            c0 = n0; c1 = n1;
        }

        // D: col = l&15 = token, row = (l>>4)*4 + reg
        int tok = lr;
        if (tok < nn) {
            int p = slist[t0 + tok];
            #pragma unroll
            for (int u = 0; u < 4; ++u) {
                int rr = r0 + lg*4 + u;
                float v = acc[u] + (kz == 0 ? b1[e*H2 + rr] : 0.f);
                hbuf[(size_t)p*H2 + rr] = v;
            }
        }
    }
}

// ---------------- expert down-proj + swiglu-in-staging + fused combine ----
// block = 256 thr = 4 waves; wave owns 16 w2 rows x 16 tokens x HIDDEN/4.
// grid (NEXP, DIM/64 = 8, 4). Staging reads h0+h1, applies swiglu, bf16.
__global__ __launch_bounds__(256, 4) void expert_down(
        const float* __restrict__ h0, const float* __restrict__ h1,
        const float* __restrict__ w2, const float* __restrict__ b2,
        const int* __restrict__ idxw, const float* __restrict__ eww,
        float* __restrict__ out) {
    int e = blockIdx.x;
    int kz = blockIdx.z;                   // HIDDEN quarter: 0..3
    int tid = threadIdx.x;
    __shared__ int slist[TOKENS];
    __shared__ unsigned long long smask[4];
    __shared__ int scnt;
    int n = build_list_ballot(idxw, e, tid, slist, smask, &scnt);
    if (n == 0) return;
    int wv = tid >> 6, l = tid & 63;
    int lr = l & 15, lg = l >> 4;
    __shared__ unsigned short as_[16][256 + PADK];   // 8.25 KB (this quarter)
    int r0 = blockIdx.y * 64 + wv * 16;    // output row tile base (0..511)
    const float4* w4 = (const float4*)(w2 + ((size_t)e*DIM + r0 + lr) * HIDDEN
                                       + kz * 256 + lg * 8);

    for (int t0 = 0; t0 < n; t0 += 16) {
        int nn = min(16, n - t0);
        __syncthreads();
        // stage quarter: act[c] = swiglu(h[2c], h[2c+1]), c in [kz*256, +256)
        for (int i = tid; i < 16 * 128; i += 256) {      // 128 h-f4 per quarter
            int j = i >> 7, dd = i & 127;
            float4 a = make_float4(0.f, 0.f, 0.f, 0.f);
            if (j < nn) {
                int p = slist[t0 + j];
                size_t off = (size_t)p*H2 + kz*512 + 4*dd;
                float4 va = *(const float4*)(h0 + off);
                float4 vb = *(const float4*)(h1 + off);
                a.x = va.x + vb.x; a.y = va.y + vb.y;
                a.z = va.z + vb.z; a.w = va.w + vb.w;
            }
            ushort2v hv;
            hv[0] = f2bf_rne(swiglu2(a.x, a.y));
            hv[1] = f2bf_rne(swiglu2(a.z, a.w));
            *(ushort2v*)&as_[j][2*dd] = hv;
        }
        __syncthreads();

        fp32x4 acc = {0.f, 0.f, 0.f, 0.f};
        float4 c0 = w4[0], c1 = w4[1];
        for (int kt = 0; kt < 8; ++kt) {
            int ktn = (kt + 1) & 7;          // branchless wrap
            float4 n0 = w4[8*ktn], n1 = w4[8*ktn + 1];
            MFMA_STEP(as_, c0, c1, kt);
            c0 = n0; c1 = n1;
        }

        int tok = lr;
        if (tok < nn) {
            int p = slist[t0 + tok];
            float ew = eww[p];
            int b = p >> 2;
            #pragma unroll
            for (int u = 0; u < 4; ++u) {
                int rr = r0 + lg*4 + u;
                float v = acc[u] + (kz == 0 ? b2[e*DIM + rr] : 0.f);
                atomicAdd(out + (size_t)b*DIM + rr, ew * v);
            }
        }
    }
}

extern "C" void kernel_launch(void* const* d_in, const int* in_sizes, int n_in,
                              void* d_out, int out_size, void* d_ws, size_t ws_size,
                              hipStream_t stream) {
    const float* x  = (const float*)d_in[0];
    const float* Wg = (const float*)d_in[1];
    const float* bg = (const float*)d_in[2];
    const float* w1 = (const float*)d_in[3];
    const float* b1 = (const float*)d_in[4];
    const float* w2 = (const float*)d_in[5];
    const float* b2 = (const float*)d_in[6];
    float* out = (float*)d_out;

    char* ws = (char*)d_ws;
    int*   idxw = (int*)(ws);                   // 256 ints
    float* eww  = (float*)(ws + 1024);          // 256 floats
    float* h0   = (float*)(ws + 16384);                          // 256*2048 f32 = 2 MB
    float* h1   = (float*)(ws + 16384 + (size_t)NPAIR*H2*4);     // 2 MB

    router_kernel<<<TOKENS, 512, 0, stream>>>(x, Wg, bg, idxw, eww, out);
    expert_up<<<dim3(NEXP, H2/64, 2), 256, 0, stream>>>(x, w1, b1, idxw, h0, h1);
    expert_down<<<dim3(NEXP, DIM/64, 4), 256, 0, stream>>>(h0, h1, w2, b2, idxw, eww, out);
}